// Round 3
// baseline (77.229 us; speedup 1.0000x reference)
//
#include <hip/hip_runtime.h>

// NLM smoothing: x[B=8, H=256, W=256, C=8] fp32, K=5, sigma=1, h=1, reflect pad.
// Block computes a 32(j) x 16(i) pixel tile with 256 threads; each thread owns
// two vertically adjacent pixels (A at i0, B at i0+1), sharing 4 of 6 halo rows
// of neighbor loads. Tile staged as TWO de-interleaved float4 planes so
// ds_read_b128 lane stride is 16B (4 dwords) -> all 32 banks used, no
// conflicts (the R1 interleaved layout had 32B stride -> half the banks idle).
// Weight fusion: gk normalization cancels in w/sum(w); spatial + intensity
// Gaussians fuse into one __expf per neighbor.

#define BATCH 8
#define NX 256
#define NY 256
#define HALO 2
#define TSJ 32           // tile width (j)
#define TSI 16           // tile height (i), 2 rows per thread
#define LW (TSJ + 2 * HALO)   // 36
#define LH (TSI + 2 * HALO)   // 20
#define NPIX (LW * LH)        // 720

__device__ __forceinline__ int reflect_idx(int v) {
    // valid for v in [-2, 257] with N=256
    if (v < 0) v = -v;
    if (v > NY - 1) v = 2 * (NY - 1) - v;
    return v;
}

__device__ __forceinline__ void contrib(const float4& c0, const float4& c1,
                                        const float4& p0, const float4& p1,
                                        float spatial,
                                        float4& a0, float4& a1, float& ws) {
    float d, t;
    t = c0.x - p0.x; d  = t * t;
    t = c0.y - p0.y; d += t * t;
    t = c0.z - p0.z; d += t * t;
    t = c0.w - p0.w; d += t * t;
    t = c1.x - p1.x; d += t * t;
    t = c1.y - p1.y; d += t * t;
    t = c1.z - p1.z; d += t * t;
    t = c1.w - p1.w; d += t * t;
    const float w = __expf(-(d + spatial));
    a0.x += w * p0.x; a0.y += w * p0.y; a0.z += w * p0.z; a0.w += w * p0.w;
    a1.x += w * p1.x; a1.y += w * p1.y; a1.z += w * p1.z; a1.w += w * p1.w;
    ws += w;
}

__global__ __launch_bounds__(256) void nlm_kernel(const float4* __restrict__ xv,
                                                  float4* __restrict__ ov) {
    __shared__ float4 t0[NPIX];
    __shared__ float4 t1[NPIX];

    const int t = threadIdx.x;
    const int bj0 = blockIdx.x * TSJ;
    const int bi0 = blockIdx.y * TSI;
    const int b = blockIdx.z;
    const int bbase = b * (NX * NY);

    // ---- stage tile (reflect halo) into de-interleaved LDS planes ----
#pragma unroll
    for (int s0 = 0; s0 < NPIX; s0 += 256) {
        const int p = s0 + t;
        if (p < NPIX) {
            const int lr = p / LW;
            const int lc = p - lr * LW;
            const int gi = reflect_idx(bi0 + lr - HALO);
            const int gj = reflect_idx(bj0 + lc - HALO);
            const int g = (bbase + gi * NY + gj) * 2;
            t0[p] = xv[g];
            t1[p] = xv[g + 1];
        }
    }
    __syncthreads();

    // ---- per-thread: two vertical pixels A (i0), B (i0+1) ----
    const int lj = t & (TSJ - 1);      // 0..31
    const int li2 = t >> 5;            // 0..7
    const int i0 = li2 * 2;            // tile-local row of pixel A

    const int cA = (i0 + HALO) * LW + (lj + HALO);
    const int cB = cA + LW;

    const float4 cA0 = t0[cA], cA1 = t1[cA];
    const float4 cB0 = t0[cB], cB1 = t1[cB];

    float4 aA0 = make_float4(0.f, 0.f, 0.f, 0.f);
    float4 aA1 = make_float4(0.f, 0.f, 0.f, 0.f);
    float4 aB0 = make_float4(0.f, 0.f, 0.f, 0.f);
    float4 aB1 = make_float4(0.f, 0.f, 0.f, 0.f);
    float wsA = 0.f, wsB = 0.f;

    const int base = i0 * LW + lj;     // padded coords of (A.i-2, j-2)

#pragma unroll
    for (int r = 0; r < 6; ++r) {      // padded rows i0 .. i0+5
#pragma unroll
        for (int dc = 0; dc < 5; ++dc) {
            const int pix = base + r * LW + dc;   // immediate offsets from base
            const float4 p0 = t0[pix];
            const float4 p1 = t1[pix];
            // pixel A window: rows r=0..4 (dr = r-2); pixel B: r=1..5 (dr = r-3)
            if (r <= 4) {
                const int drA = r - 2, dcc = dc - 2;
                contrib(cA0, cA1, p0, p1, 0.5f * (float)(drA * drA + dcc * dcc),
                        aA0, aA1, wsA);
            }
            if (r >= 1) {
                const int drB = r - 3, dcc = dc - 2;
                contrib(cB0, cB1, p0, p1, 0.5f * (float)(drB * drB + dcc * dcc),
                        aB0, aB1, wsB);
            }
        }
    }

    const float invA = 1.0f / wsA;
    const float invB = 1.0f / wsB;
    float4 oA0, oA1, oB0, oB1;
    oA0.x = aA0.x * invA; oA0.y = aA0.y * invA; oA0.z = aA0.z * invA; oA0.w = aA0.w * invA;
    oA1.x = aA1.x * invA; oA1.y = aA1.y * invA; oA1.z = aA1.z * invA; oA1.w = aA1.w * invA;
    oB0.x = aB0.x * invB; oB0.y = aB0.y * invB; oB0.z = aB0.z * invB; oB0.w = aB0.w * invB;
    oB1.x = aB1.x * invB; oB1.y = aB1.y * invB; oB1.z = aB1.z * invB; oB1.w = aB1.w * invB;

    const int oA_idx = bbase + (bi0 + i0) * NY + (bj0 + lj);
    const int oB_idx = oA_idx + NY;
    ov[oA_idx * 2 + 0] = oA0;
    ov[oA_idx * 2 + 1] = oA1;
    ov[oB_idx * 2 + 0] = oB0;
    ov[oB_idx * 2 + 1] = oB1;
}

extern "C" void kernel_launch(void* const* d_in, const int* in_sizes, int n_in,
                              void* d_out, int out_size, void* d_ws, size_t ws_size,
                              hipStream_t stream) {
    const float4* x = (const float4*)d_in[0];
    float4* out = (float4*)d_out;
    dim3 grid(NY / TSJ, NX / TSI, BATCH);  // 8 x 16 x 8 = 1024 blocks
    nlm_kernel<<<grid, 256, 0, stream>>>(x, out);
}